// Round 6
// baseline (365.943 us; speedup 1.0000x reference)
//
#include <hip/hip_runtime.h>
#include <hip/hip_bf16.h>
#include <math.h>

// Problem constants (B=2, T=2048, C=2048, NH=16, NKV=4, D=128, HALF=64)
#define BB 2
#define TT 2048
#define CC 2048
#define NH 16
#define NKV 4
#define HD 128
#define HALF 64
#define MTOT (BB*TT)            // 4096
#define NQKV (CC + 2*NKV*HD)    // 3072 (fused q|k|v columns)

typedef unsigned short u16;
typedef __attribute__((ext_vector_type(8))) short bf16x8;
typedef __attribute__((ext_vector_type(4))) float f32x4;

// fp32 -> bf16 (round-to-nearest-even), bit-twiddle form
__device__ __forceinline__ u16 f2bf(float f) {
  unsigned u = __float_as_uint(f);
  unsigned r = (u + 0x7FFFu + ((u >> 16) & 1u)) >> 16;
  return (u16)r;
}
// fp32 -> bf16 via HW convert (RNE, identical results; 1 VALU op vs 4)
__device__ __forceinline__ u16 f2bf_hw(float f) {
  __hip_bfloat16 h = __float2bfloat16(f);
  return *reinterpret_cast<const u16*>(&h);
}
__device__ __forceinline__ float bf2f(u16 v) {
  return __uint_as_float(((unsigned)v) << 16);
}

// async global->LDS, 16B per lane; lds base must be wave-uniform (HW adds lane*16)
__device__ __forceinline__ void gl_lds16(const void* g, void* l) {
  __builtin_amdgcn_global_load_lds(
      (const __attribute__((address_space(1))) unsigned int*)g,
      (__attribute__((address_space(3))) unsigned int*)l, 16, 0, 0);
}

// ---------------------------------------------------------------------------
// prep: fused x->bf16 convert (z=4) + 4 weight transposes (z=0..3).
// grid (64, 64, 5), block (32, 8).
// ---------------------------------------------------------------------------
__global__ __launch_bounds__(256) void prep(
    const float* __restrict__ x, const float* __restrict__ Wq,
    const float* __restrict__ Wk, const float* __restrict__ Wv,
    const float* __restrict__ Wo, u16* __restrict__ xb,
    u16* __restrict__ Wt, u16* __restrict__ Wot) {
  const int z = blockIdx.z;
  const int tx = threadIdx.x, ty = threadIdx.y;
  if (z == 4) {
    const int tid = ty * 32 + tx;
    const int i = (blockIdx.y * 64 + blockIdx.x) * 256 + tid;  // 8-elem group
    const float4* s4 = (const float4*)x;
    float4 a = s4[(size_t)i * 2], b = s4[(size_t)i * 2 + 1];
    bf16x8 o;
    o[0] = (short)f2bf(a.x); o[1] = (short)f2bf(a.y);
    o[2] = (short)f2bf(a.z); o[3] = (short)f2bf(a.w);
    o[4] = (short)f2bf(b.x); o[5] = (short)f2bf(b.y);
    o[6] = (short)f2bf(b.z); o[7] = (short)f2bf(b.w);
    ((bf16x8*)xb)[i] = o;
    return;
  }
  const float* W; u16* dst; int N; int row_off;
  if (z == 0)      { W = Wq; dst = Wt;  N = 2048; row_off = 0; }
  else if (z == 1) { W = Wk; dst = Wt;  N = 512;  row_off = 2048; }
  else if (z == 2) { W = Wv; dst = Wt;  N = 512;  row_off = 2560; }
  else             { W = Wo; dst = Wot; N = 2048; row_off = 0; }
  const int n0 = blockIdx.x * 32, k0 = blockIdx.y * 32;
  if (n0 >= N) return;
  __shared__ float tile[32][33];
#pragma unroll
  for (int i = 0; i < 4; ++i)
    tile[ty + 8 * i][tx] = W[(size_t)(k0 + ty + 8 * i) * N + n0 + tx];
  __syncthreads();
#pragma unroll
  for (int i = 0; i < 4; ++i)
    dst[(size_t)(row_off + n0 + ty + 8 * i) * CC + k0 + tx] =
        f2bf(tile[tx][ty + 8 * i]);
}

// ---------------------------------------------------------------------------
// 256x256 8-phase bf16 MFMA GEMM (m201-style template, plain HIP).
// Verified r2: conflicts ~0, swizzle byte^=((row&7)<<4) both sides.
// ---------------------------------------------------------------------------
__global__ __launch_bounds__(512, 2) void gemm_8ph(
    const u16* __restrict__ A, const u16* __restrict__ Bt,
    const float* __restrict__ bias, float* __restrict__ C,
    int M, int N, int K, int out_bf16) {
  __shared__ u16 As[32768];   // 2 x (256x64) bf16 = 2 x 32 KB
  __shared__ u16 Bs[32768];
  const int tid = threadIdx.x;
  const int w = tid >> 6, lane = tid & 63;
  const int quad = lane >> 4, lo = lane & 15;
  const int wm = w >> 2, wn = w & 3;          // 2M x 4N wave grid
  const int bm = blockIdx.y * 256, bn = blockIdx.x * 256;
  const int NT = K >> 6;                      // K-tiles of 64 (NT >= 2)

  const u16* agp[2][2]; const u16* bgp[2][2];
#pragma unroll
  for (int h = 0; h < 2; ++h)
#pragma unroll
    for (int j = 0; j < 2; ++j) {
      const unsigned X = (unsigned)h * 16384u +
                         (unsigned)((w * 2 + j) * 64 + lane) * 16u;
      const int row = (int)(X >> 7);
      const int ce = (int)(((X & 127u) ^ (((X >> 7) & 7u) << 4)) >> 1);
      agp[h][j] = A  + (size_t)(bm + row) * K + ce;
      bgp[h][j] = Bt + (size_t)(bn + row) * K + ce;
    }
  char* const lAs = (char*)As;
  char* const lBs = (char*)Bs;
  const int woff = w * 2048;

#define STGA(hh, bufp, kt) do { \
    gl_lds16(agp[hh][0] + (size_t)(kt) * 64, lAs + (bufp) * 32768 + (hh) * 16384 + woff); \
    gl_lds16(agp[hh][1] + (size_t)(kt) * 64, lAs + (bufp) * 32768 + (hh) * 16384 + woff + 1024); \
  } while (0)
#define STGB(hh, bufp, kt) do { \
    gl_lds16(bgp[hh][0] + (size_t)(kt) * 64, lBs + (bufp) * 32768 + (hh) * 16384 + woff); \
    gl_lds16(bgp[hh][1] + (size_t)(kt) * 64, lBs + (bufp) * 32768 + (hh) * 16384 + woff + 1024); \
  } while (0)

  const int sw  = (lo & 7) << 4;
  const int co0 = (quad * 16) ^ sw;
  const int co1 = (64 + quad * 16) ^ sw;
  const int aRB = (wm * 128 + lo) * 128;      // + qr*8192 + i*2048
  const int bRB = (wn * 64 + lo) * 128;       // + qc*4096 + j*2048

  f32x4 acc[8][4];
#pragma unroll
  for (int ri = 0; ri < 8; ++ri)
#pragma unroll
    for (int ci = 0; ci < 4; ++ci)
#pragma unroll
      for (int r = 0; r < 4; ++r) acc[ri][ci][r] = 0.f;

  STGA(0, 0, 0); STGA(1, 0, 0); STGB(0, 0, 0); STGB(1, 0, 0);
  STGB(0, 1, 1); STGB(1, 1, 1); STGA(0, 1, 1);
  asm volatile("s_waitcnt vmcnt(6)" ::: "memory");
  __builtin_amdgcn_s_barrier();

  for (int t = 0; t < NT; ++t) {
    const int pa = t & 1;
    const char* Ab = lAs + pa * 32768 + aRB;
    const char* Bb = lBs + pa * 32768 + bRB;
    bf16x8 a[4][2], b0[2][2], b1[2][2];

    // ---- phase 0: quadrant (qr=0, qc=0) --------------------------------
#pragma unroll
    for (int i = 0; i < 4; ++i) {
      a[i][0] = *(const bf16x8*)(Ab + i * 2048 + co0);
      a[i][1] = *(const bf16x8*)(Ab + i * 2048 + co1);
    }
#pragma unroll
    for (int j = 0; j < 2; ++j) {
      b0[j][0] = *(const bf16x8*)(Bb + j * 2048 + co0);
      b0[j][1] = *(const bf16x8*)(Bb + j * 2048 + co1);
    }
    if (t + 1 < NT) STGA(1, (t + 1) & 1, t + 1);
    __builtin_amdgcn_s_barrier();
    asm volatile("s_waitcnt lgkmcnt(0)");
    __builtin_amdgcn_s_setprio(1);
#pragma unroll
    for (int i = 0; i < 4; ++i)
#pragma unroll
      for (int j = 0; j < 2; ++j) {
        acc[i][j] = __builtin_amdgcn_mfma_f32_16x16x32_bf16(a[i][0], b0[j][0], acc[i][j], 0, 0, 0);
        acc[i][j] = __builtin_amdgcn_mfma_f32_16x16x32_bf16(a[i][1], b0[j][1], acc[i][j], 0, 0, 0);
      }
    __builtin_amdgcn_s_setprio(0);
    __builtin_amdgcn_s_barrier();

    // ---- phase 1: quadrant (qr=0, qc=1) --------------------------------
#pragma unroll
    for (int j = 0; j < 2; ++j) {
      b1[j][0] = *(const bf16x8*)(Bb + 4096 + j * 2048 + co0);
      b1[j][1] = *(const bf16x8*)(Bb + 4096 + j * 2048 + co1);
    }
    __builtin_amdgcn_s_barrier();
    asm volatile("s_waitcnt lgkmcnt(0)");
    __builtin_amdgcn_s_setprio(1);
#pragma unroll
    for (int i = 0; i < 4; ++i)
#pragma unroll
      for (int j = 0; j < 2; ++j) {
        acc[i][2 + j] = __builtin_amdgcn_mfma_f32_16x16x32_bf16(a[i][0], b1[j][0], acc[i][2 + j], 0, 0, 0);
        acc[i][2 + j] = __builtin_amdgcn_mfma_f32_16x16x32_bf16(a[i][1], b1[j][1], acc[i][2 + j], 0, 0, 0);
      }
    __builtin_amdgcn_s_setprio(0);
    __builtin_amdgcn_s_barrier();

    // ---- phase 2: quadrant (qr=1, qc=1) --------------------------------
#pragma unroll
    for (int i = 0; i < 4; ++i) {
      a[i][0] = *(const bf16x8*)(Ab + 8192 + i * 2048 + co0);
      a[i][1] = *(const bf16x8*)(Ab + 8192 + i * 2048 + co1);
    }
    if (t + 2 < NT) STGB(0, pa, t + 2);
    __builtin_amdgcn_s_barrier();
    asm volatile("s_waitcnt lgkmcnt(0)");
    __builtin_amdgcn_s_setprio(1);
#pragma unroll
    for (int i = 0; i < 4; ++i)
#pragma unroll
      for (int j = 0; j < 2; ++j) {
        acc[4 + i][2 + j] = __builtin_amdgcn_mfma_f32_16x16x32_bf16(a[i][0], b1[j][0], acc[4 + i][2 + j], 0, 0, 0);
        acc[4 + i][2 + j] = __builtin_amdgcn_mfma_f32_16x16x32_bf16(a[i][1], b1[j][1], acc[4 + i][2 + j], 0, 0, 0);
      }
    __builtin_amdgcn_s_setprio(0);
    __builtin_amdgcn_s_barrier();

    // ---- phase 3: quadrant (qr=1, qc=0); counted wait ------------------
    if (t + 2 < NT) { STGB(1, pa, t + 2); STGA(0, pa, t + 2); }
    if (t + 2 < NT)      asm volatile("s_waitcnt vmcnt(6)" ::: "memory");
    else if (t + 1 < NT) asm volatile("s_waitcnt vmcnt(0)" ::: "memory");
    __builtin_amdgcn_s_barrier();
    asm volatile("s_waitcnt lgkmcnt(0)");
    __builtin_amdgcn_s_setprio(1);
#pragma unroll
    for (int i = 0; i < 4; ++i)
#pragma unroll
      for (int j = 0; j < 2; ++j) {
        acc[4 + i][j] = __builtin_amdgcn_mfma_f32_16x16x32_bf16(a[i][0], b0[j][0], acc[4 + i][j], 0, 0, 0);
        acc[4 + i][j] = __builtin_amdgcn_mfma_f32_16x16x32_bf16(a[i][1], b0[j][1], acc[4 + i][j], 0, 0, 0);
      }
    __builtin_amdgcn_s_setprio(0);
    __builtin_amdgcn_s_barrier();
  }
#undef STGA
#undef STGB

  const int rbase = bm + wm * 128;
  const int cbase = bn + wn * 64;
#pragma unroll
  for (int ri = 0; ri < 8; ++ri)
#pragma unroll
    for (int ci = 0; ci < 4; ++ci) {
      const int col = cbase + ci * 16 + lo;
      const float bv = bias ? bias[col] : 0.f;
#pragma unroll
      for (int r = 0; r < 4; ++r) {
        const int row = rbase + ri * 16 + quad * 4 + r;
        const float v = acc[ri][ci][r] + bv;
        if (out_bf16) ((u16*)C)[(size_t)row * N + col] = f2bf(v);
        else          C[(size_t)row * N + col] = v;
      }
    }
}

// ---------------------------------------------------------------------------
// 256x128 2-phase bf16 MFMA GEMM — grid-fill variant for the out-proj
// (N=2048 -> 16x16 = 256 blocks = 1/CU). Verified r4.
// ---------------------------------------------------------------------------
__global__ __launch_bounds__(512, 2) void gemm_n128(
    const u16* __restrict__ A, const u16* __restrict__ Bt,
    const float* __restrict__ bias, float* __restrict__ C,
    int M, int N, int K, int out_bf16) {
  __shared__ u16 As[32768];   // 2 x (256x64) bf16
  __shared__ u16 Bs[16384];   // 2 x (128x64) bf16
  const int tid = threadIdx.x;
  const int w = tid >> 6, lane = tid & 63;
  const int quad = lane >> 4, lo = lane & 15;
  const int wm = w >> 1, wn = w & 1;          // 4M x 2N wave grid
  const int bm = blockIdx.y * 256, bn = blockIdx.x * 128;
  const int NT = K >> 6;                      // K-tiles of 64 (NT >= 3)

  const u16* agp[2][2];
#pragma unroll
  for (int h = 0; h < 2; ++h)
#pragma unroll
    for (int j = 0; j < 2; ++j) {
      const unsigned X = (unsigned)h * 16384u +
                         (unsigned)((w * 2 + j) * 64 + lane) * 16u;
      const int row = (int)(X >> 7);
      const int ce = (int)(((X & 127u) ^ (((X >> 7) & 7u) << 4)) >> 1);
      agp[h][j] = A + (size_t)(bm + row) * K + ce;
    }
  const u16* bgp[2];
#pragma unroll
  for (int j = 0; j < 2; ++j) {
    const unsigned X = (unsigned)((w * 2 + j) * 64 + lane) * 16u;
    const int row = (int)(X >> 7);
    const int ce = (int)(((X & 127u) ^ (((X >> 7) & 7u) << 4)) >> 1);
    bgp[j] = Bt + (size_t)(bn + row) * K + ce;
  }
  char* const lAs = (char*)As;
  char* const lBs = (char*)Bs;
  const int woff = w * 2048;

#define STGA_(hh, bufp, kt) do { \
    gl_lds16(agp[hh][0] + (size_t)(kt) * 64, lAs + (bufp) * 32768 + (hh) * 16384 + woff); \
    gl_lds16(agp[hh][1] + (size_t)(kt) * 64, lAs + (bufp) * 32768 + (hh) * 16384 + woff + 1024); \
  } while (0)
#define STGB_(bufp, kt) do { \
    gl_lds16(bgp[0] + (size_t)(kt) * 64, lBs + (bufp) * 16384 + woff); \
    gl_lds16(bgp[1] + (size_t)(kt) * 64, lBs + (bufp) * 16384 + woff + 1024); \
  } while (0)

  const int sw  = (lo & 7) << 4;
  const int co0 = (quad * 16) ^ sw;
  const int co1 = (64 + quad * 16) ^ sw;
  const int aRB = (wm * 64 + lo) * 128;       // + i*2048
  const int bRB = (wn * 64 + lo) * 128;       // + ci*2048

  f32x4 acc[4][4];
#pragma unroll
  for (int i = 0; i < 4; ++i)
#pragma unroll
    for (int ci = 0; ci < 4; ++ci)
#pragma unroll
      for (int r = 0; r < 4; ++r) acc[i][ci][r] = 0.f;

  STGA_(0, 0, 0); STGA_(1, 0, 0); STGB_(0, 0);
  STGB_(1, 1); STGA_(0, 1, 1);
  asm volatile("s_waitcnt vmcnt(4)" ::: "memory");
  __builtin_amdgcn_s_barrier();

  for (int t = 0; t < NT; ++t) {
    const int pa = t & 1;
    const char* Ab = lAs + pa * 32768 + aRB;
    const char* Bb = lBs + pa * 16384 + bRB;
    bf16x8 a[4][2], b[4][2];
#pragma unroll
    for (int i = 0; i < 4; ++i) {
      a[i][0] = *(const bf16x8*)(Ab + i * 2048 + co0);
      a[i][1] = *(const bf16x8*)(Ab + i * 2048 + co1);
    }
#pragma unroll
    for (int ci = 0; ci < 4; ++ci) {
      b[ci][0] = *(const bf16x8*)(Bb + ci * 2048 + co0);
      b[ci][1] = *(const bf16x8*)(Bb + ci * 2048 + co1);
    }
    if (t + 1 < NT) STGA_(1, (t + 1) & 1, t + 1);
    asm volatile("s_waitcnt lgkmcnt(0)");   // own reads done BEFORE barrier
    __builtin_amdgcn_s_barrier();           // -> all waves' reads of buf pa done
    __builtin_amdgcn_s_setprio(1);
#pragma unroll
    for (int i = 0; i < 4; ++i)
#pragma unroll
      for (int ci = 0; ci < 2; ++ci) {
        acc[i][ci] = __builtin_amdgcn_mfma_f32_16x16x32_bf16(a[i][0], b[ci][0], acc[i][ci], 0, 0, 0);
        acc[i][ci] = __builtin_amdgcn_mfma_f32_16x16x32_bf16(a[i][1], b[ci][1], acc[i][ci], 0, 0, 0);
      }
    __builtin_amdgcn_s_setprio(0);
    if (t + 2 < NT) { STGB_(pa, t + 2); STGA_(0, pa, t + 2); }
    if (t + 2 < NT)      asm volatile("s_waitcnt vmcnt(4)" ::: "memory");
    else if (t + 1 < NT) asm volatile("s_waitcnt vmcnt(0)" ::: "memory");
    __builtin_amdgcn_s_setprio(1);
#pragma unroll
    for (int i = 0; i < 4; ++i)
#pragma unroll
      for (int ci = 2; ci < 4; ++ci) {
        acc[i][ci] = __builtin_amdgcn_mfma_f32_16x16x32_bf16(a[i][0], b[ci][0], acc[i][ci], 0, 0, 0);
        acc[i][ci] = __builtin_amdgcn_mfma_f32_16x16x32_bf16(a[i][1], b[ci][1], acc[i][ci], 0, 0, 0);
      }
    __builtin_amdgcn_s_setprio(0);
    __builtin_amdgcn_s_barrier();           // next iter reads need all DMAs in
  }
#undef STGA_
#undef STGB_

  const int rbase = bm + wm * 64;
  const int cbase = bn + wn * 64;
#pragma unroll
  for (int i = 0; i < 4; ++i)
#pragma unroll
    for (int ci = 0; ci < 4; ++ci) {
      const int col = cbase + ci * 16 + lo;
      const float bv = bias ? bias[col] : 0.f;
#pragma unroll
      for (int r = 0; r < 4; ++r) {
        const int row = rbase + i * 16 + quad * 4 + r;
        const float v = acc[i][ci][r] + bv;
        if (out_bf16) ((u16*)C)[(size_t)row * N + col] = f2bf(v);
        else          C[(size_t)row * N + col] = v;
      }
    }
}

// ---------------------------------------------------------------------------
// RMSNorm + RoPE from bf16 qkv_lin, one wave per (b,t,head). grid (B*T, 5).
// ---------------------------------------------------------------------------
__global__ __launch_bounds__(256) void qkv_post(
    const u16* __restrict__ qkv_lin, const float* __restrict__ cosp,
    const float* __restrict__ sinp, u16* __restrict__ q, u16* __restrict__ k) {
  const int bt = blockIdx.x;
  const int hh = blockIdx.y * 4 + (threadIdx.x >> 6);   // 0..19
  const int lane = threadIdx.x & 63;
  const int t = bt & (TT - 1), b = bt >> 11;
  const int col = (hh < NH) ? hh * HD : CC + (hh - NH) * HD;
  const u16* src = qkv_lin + (size_t)bt * NQKV + col;
  float v1 = bf2f(src[lane]), v2 = bf2f(src[lane + 64]);
  float ss = v1 * v1 + v2 * v2;
#pragma unroll
  for (int mm = 1; mm < 64; mm <<= 1) ss += __shfl_xor(ss, mm, 64);
  float rms = rsqrtf(ss * (1.f / 128.f) + 1.1920929e-7f);
  float c = cosp[t * HALF + lane], s = sinp[t * HALF + lane];
  float o1 = v1 * rms * c - v2 * rms * s;
  float o2 = v1 * rms * s + v2 * rms * c;
  if (hh < NH) {
    u16* dst = q + (((size_t)(b * NH + hh)) * TT + t) * HD;
    dst[lane] = f2bf(o1); dst[lane + 64] = f2bf(o2);
  } else {
    u16* dst = k + (((size_t)(b * NKV + (hh - NH))) * TT + t) * HD;
    dst[lane] = f2bf(o1); dst[lane + 64] = f2bf(o2);
  }
}

// ---------------------------------------------------------------------------
// v part of qkv_lin (bf16) -> vt (B,KV,D,T) with kv PERMUTED within each
// 32-block: stored position p(kv) = ((kv>>2)&3)*8 + (kv&3) + 4*((kv>>4)&1).
// ---------------------------------------------------------------------------
__global__ __launch_bounds__(256) void v_transpose(
    const u16* __restrict__ qkv_lin, u16* __restrict__ vt) {
  __shared__ u16 tile[32][33];
  const int t0 = blockIdx.x * 32, d0 = blockIdx.y * 32;
  const int p = blockIdx.z;             // b*NKV + kv
  const int b = p >> 2, kv = p & 3;
  const int tx = threadIdx.x, ty = threadIdx.y;
#pragma unroll
  for (int i = 0; i < 4; ++i)
    tile[ty + 8 * i][tx] =
        qkv_lin[(size_t)(b * TT + t0 + ty + 8 * i) * NQKV + CC + NKV * HD + kv * HD + d0 + tx];
  __syncthreads();
  const int tperm = ((tx >> 2) & 3) * 8 + (tx & 3) + 4 * ((tx >> 4) & 1);
#pragma unroll
  for (int i = 0; i < 4; ++i)
    vt[((size_t)p * HD + d0 + ty + 8 * i) * TT + t0 + tperm] = tile[tx][ty + 8 * i];
}

// ---------------------------------------------------------------------------
// S^T softmax + A-fragment pack, all in registers (v5-verified math).
// r5: f2bf_hw (v_cvt) replaces the 4-op bit-twiddle in the pack (~64->16 VALU).
// ---------------------------------------------------------------------------
__device__ __forceinline__ void softmax_pack(
    const f32x4* sacc, float& l_lane, bf16x8* ap, int rowq, int t0,
    bool diag, int quad) {
  const float cc = 0.12751744050808612f;   // log2(e)/sqrt(128)
  float e[4][4];
  if (diag) {
#pragma unroll
    for (int ct = 0; ct < 4; ++ct)
#pragma unroll
      for (int r = 0; r < 4; ++r) {
        float v = __builtin_amdgcn_exp2f(sacc[ct][r] * cc);
        if (t0 + ct * 16 + quad * 4 + r > rowq) v = 0.f;
        l_lane += v; e[ct][r] = v;
      }
  } else {
#pragma unroll
    for (int ct = 0; ct < 4; ++ct)
#pragma unroll
      for (int r = 0; r < 4; ++r) {
        float v = __builtin_amdgcn_exp2f(sacc[ct][r] * cc);
        l_lane += v; e[ct][r] = v;
      }
  }
#pragma unroll
  for (int k2 = 0; k2 < 2; ++k2) {
    bf16x8 ch;
#pragma unroll
    for (int j = 0; j < 8; ++j)
      ch[j] = (short)f2bf_hw(e[k2 * 2 + (j >> 2)][j & 3]);
    ap[k2] = ch;
  }
}

// ---------------------------------------------------------------------------
// MFMA flash attention v8: v7 rb-split + DEPTH-2 PREFETCH (triple buffer).
// grid (16, 32), block 512 (8 waves; waves 0-3 tile A, 4-7 tile B).
// LDS 96 KB (K,V each 3 x 16 KB) -> 1 block/CU. Loop head replaces
// __syncthreads with counted vmcnt + raw s_barrier: tile nt's 4 loads/wave
// were issued 2 iterations ago -> vmcnt(4) (allow tile nt+1's 4 newest in
// flight) is ~free; the load transfer overlaps 2 compute phases.
// Buffer legality: iter nt stages tile nt+2 into buf[(nt+2)%3]; its readers
// (iter nt-1, same buf index) precede iter nt's barrier in program order.
// Last-iter edge: no stage issued -> vmcnt(0). ntiles >= 17 so the 2-tile
// prologue is always valid. Fragment math/masks/epilogue identical to v7.
// ---------------------------------------------------------------------------
__global__ __launch_bounds__(512, 2) void attn_mfma(
    const u16* __restrict__ Qb, const u16* __restrict__ Kb,
    const u16* __restrict__ Vt, u16* __restrict__ Y) {
  __shared__ u16 Ks[3][8192];   // 16 sets (ct*4+kc) x 512, triple-buffered
  __shared__ u16 Vs[3][8192];   // 16 sets (dt*2+k2) x 512, triple-buffered

  const int qt = blockIdx.x;    // pair (qt, 31-qt)
  const int bh = blockIdx.y;
  const int b = bh >> 4, h = bh & 15, kvh = h >> 2;
  const int tid = threadIdx.x;
  const int wave = tid >> 6, lane = tid & 63;
  const int wg = wave >> 2, wv = wave & 3;   // wg: 0 = tile A, 1 = tile B
  const int quad = lane >> 4, lo = lane & 15;

  const int rows = (wg == 0) ? qt * 64 : (31 - qt) * 64;
  const u16* Qg = Qb + (size_t)(b * NH + h) * TT * HD;
  const u16* Kg = Kb + (size_t)(b * NKV + kvh) * TT * HD;
  const u16* Vg = Vt + (size_t)(b * NKV + kvh) * HD * TT;

  // Q fragments, used as MFMA B-operand (n=lo -> q-row, k=quad*8+j)
  bf16x8 aq[4];
#pragma unroll
  for (int kc = 0; kc < 4; ++kc)
    aq[kc] = *(const bf16x8*)(Qg + (size_t)(rows + wv * 16 + lo) * HD + kc * 32 + quad * 8);

  // staging: wave stages K sets {wave*2, wave*2+1} and V sets {wave*2, wave*2+1}
  const u16* kgp[2]; const u16* vgp[2];
  u16* klp[3][2]; u16* vlp[3][2];
#pragma unroll
  for (int c = 0; c < 2; ++c) {
    const int s = wave * 2 + c;          // 0..15
    const int ct = s >> 2, kq = s & 3;
    kgp[c] = Kg + (size_t)(ct * 16 + lo) * HD + kq * 32 + quad * 8;
    const int dt = s >> 1, k2 = s & 1;
    vgp[c] = Vg + (size_t)(dt * 16 + lo) * TT + k2 * 32 + quad * 8;
#pragma unroll
    for (int p = 0; p < 3; ++p) {
      klp[p][c] = &Ks[p][s * 512];
      vlp[p][c] = &Vs[p][s * 512];
    }
  }

  f32x4 oacc[8];
#pragma unroll
  for (int dt = 0; dt < 8; ++dt)
#pragma unroll
    for (int r = 0; r < 4; ++r) oacc[dt][r] = 0.f;
  float l_lane = 0.f;

  const int ntiles = 32 - qt;              // >= 17
  const int rowq = rows + wv * 16 + lo;    // this lane's q-row

  // prologue: stage tiles 0 -> buf0 and 1 -> buf1 (depth-2)
#pragma unroll
  for (int c = 0; c < 2; ++c) {
    gl_lds16(kgp[c], klp[0][c]); kgp[c] += 64 * HD;
    gl_lds16(vgp[c], vlp[0][c]); vgp[c] += 64;
  }
#pragma unroll
  for (int c = 0; c < 2; ++c) {
    gl_lds16(kgp[c], klp[1][c]); kgp[c] += 64 * HD;
    gl_lds16(vgp[c], vlp[1][c]); vgp[c] += 64;
  }

  int par = 0;
  for (int nt = 0; nt < ntiles; ++nt) {
    // tile nt landed? (its 4 loads are the oldest; 4 newest = tile nt+1)
    if (nt + 1 < ntiles) asm volatile("s_waitcnt vmcnt(4)" ::: "memory");
    else                 asm volatile("s_waitcnt vmcnt(0)" ::: "memory");
    __builtin_amdgcn_s_barrier();   // all waves' tile-nt loads in; all waves'
                                    // iter nt-1 reads of buf[(nt+2)%3] done
    if (nt + 2 < ntiles) {
      const int ps = (nt + 2 < 3) ? (nt + 2) : (nt + 2) % 3;
#pragma unroll
      for (int c = 0; c < 2; ++c) {
        gl_lds16(kgp[c], klp[ps][c]); kgp[c] += 64 * HD;
        gl_lds16(vgp[c], vlp[ps][c]); vgp[c] += 64;
      }
    }
    const bool act = (wg == 1) || (nt <= qt);
    if (act) {
      const u16* ksb = Ks[par];
      const u16* vsb = Vs[par];
      const int t0 = nt * 64;

      // S^T = K Q^T: D row (quad*4+r) = kv, col (lo) = q-row
      f32x4 sacc[4];
#pragma unroll
      for (int ct = 0; ct < 4; ++ct)
#pragma unroll
        for (int r = 0; r < 4; ++r) sacc[ct][r] = 0.f;
      __builtin_amdgcn_s_setprio(1);
#pragma unroll
      for (int ct = 0; ct < 4; ++ct)
#pragma unroll
        for (int kc = 0; kc < 4; ++kc) {
          bf16x8 bk = *(const bf16x8*)&ksb[(ct * 4 + kc) * 512 + lane * 8];
          sacc[ct] = __builtin_amdgcn_mfma_f32_16x16x32_bf16(bk, aq[kc], sacc[ct], 0, 0, 0);
        }
      __builtin_amdgcn_s_setprio(0);

      // softmax + register P pack
      bf16x8 ap[2];
      softmax_pack(sacc, l_lane, ap, rowq, t0, t0 + 63 > rows + wv * 16, quad);

      // O += P @ V  (V already in permuted kv order matching the pack)
      __builtin_amdgcn_s_setprio(1);
#pragma unroll
      for (int dt = 0; dt < 8; ++dt)
#pragma unroll
        for (int k2 = 0; k2 < 2; ++k2) {
          bf16x8 bv = *(const bf16x8*)&vsb[(dt * 2 + k2) * 512 + lane * 8];
          oacc[dt] = __builtin_amdgcn_mfma_f32_16x16x32_bf16(ap[k2], bv, oacc[dt], 0, 0, 0);
        }
      __builtin_amdgcn_s_setprio(0);
    }
    par = (par == 2) ? 0 : par + 1;
  }

  // epilogue: l for q-row `lo` -> reduce over quad lanes; fetch per-output-row
  float l = l_lane;
  l += __shfl_xor(l, 16, 64);
  l += __shfl_xor(l, 32, 64);
  l = 1.f / l;                       // valid at lane lo for row lo (all quads)
  float linv[4];
#pragma unroll
  for (int r = 0; r < 4; ++r)
    linv[r] = __shfl(l, quad * 4 + r, 64);   // row quad*4+r lives at lane quad*4+r
  const size_t row0 = (size_t)b * TT + rows + wv * 16 + quad * 4;
#pragma unroll
  for (int dt = 0; dt < 8; ++dt)
#pragma unroll
    for (int r = 0; r < 4; ++r)
      Y[(row0 + r) * CC + h * HD + dt * 16 + lo] = f2bf(oacc[dt][r] * linv[r]);
}

// ---------------------------------------------------------------------------
// kernel_launch. ws layout (bytes):
//   [0,16M):   xb (bf16 x)            -> later qb_buf (bf16 q, B,H,T,D)
//   [16M,28M): Wt (bf16 qkv^T)        -> later kb (4M) + vt (8M)
//   [28M,52M): qkv_lin bf16 (M x 3072)-> first 16M later y (bf16, M x C)
//   [52M,60M): Wot (bf16 Wo^T)
// ---------------------------------------------------------------------------
extern "C" void kernel_launch(void* const* d_in, const int* in_sizes, int n_in,
                              void* d_out, int out_size, void* d_ws, size_t ws_size,
                              hipStream_t stream) {
  (void)in_sizes; (void)n_in; (void)out_size; (void)ws_size;
  const float* x    = (const float*)d_in[0];
  const float* cosp = (const float*)d_in[1];
  const float* sinp = (const float*)d_in[2];
  const float* Wq   = (const float*)d_in[3];
  const float* Wk   = (const float*)d_in[4];
  const float* Wv   = (const float*)d_in[5];
  const float* Wo   = (const float*)d_in[6];
  const float* bo   = (const float*)d_in[7];
  float* out = (float*)d_out;
  char* ws = (char*)d_ws;

  const size_t MB = 1024 * 1024;
  u16* xb      = (u16*)(ws);
  u16* Wt      = (u16*)(ws + 16 * MB);
  u16* qkv_lin = (u16*)(ws + 28 * MB);
  u16* Wot     = (u16*)(ws + 52 * MB);
  u16* qb_buf  = (u16*)(ws);             // alias xb (dead after GEMM1)
  u16* kb      = (u16*)(ws + 16 * MB);   // alias Wt
  u16* vt      = (u16*)(ws + 20 * MB);   // alias Wt+4M
  u16* y       = (u16*)(ws + 28 * MB);   // alias qkv_lin head (dead after post)

  // 1. fused convert + weight transposes
  prep<<<dim3(64, 64, 5), dim3(32, 8), 0, stream>>>(x, Wq, Wk, Wv, Wo, xb, Wt, Wot);

  // 2. fused QKV GEMM (M=4096, N=3072, K=2048), bf16 out
  gemm_8ph<<<dim3(NQKV / 256, MTOT / 256), 512, 0, stream>>>(
      xb, Wt, nullptr, (float*)qkv_lin, MTOT, NQKV, CC, 1);

  // 3. RMSNorm + RoPE -> bf16 q/k head-major
  qkv_post<<<dim3(MTOT, 5), 256, 0, stream>>>(qkv_lin, cosp, sinp, qb_buf, kb);

  // 4. V -> (B,KV,D,T) bf16, kv-permuted
  v_transpose<<<dim3(TT / 32, HD / 32, BB * NKV), dim3(32, 8), 0, stream>>>(qkv_lin, vt);

  // 5. MFMA flash attention v8 (depth-2 prefetch) -> y bf16 (M x C)
  attn_mfma<<<dim3(16, BB * NH), 512, 0, stream>>>(qb_buf, kb, vt, y);

  // 6. out-proj GEMM + bias (fp32 out) — 256x128 tiles: 256 blocks = 1/CU
  gemm_n128<<<dim3(CC / 128, MTOT / 256), 512, 0, stream>>>(
      y, Wot, bo, out, MTOT, CC, CC, 0);
}

// Round 7
// 304.366 us; speedup vs baseline: 1.2023x; 1.2023x over previous
//
#include <hip/hip_runtime.h>
#include <hip/hip_bf16.h>
#include <math.h>

// Problem constants (B=2, T=2048, C=2048, NH=16, NKV=4, D=128, HALF=64)
#define BB 2
#define TT 2048
#define CC 2048
#define NH 16
#define NKV 4
#define HD 128
#define HALF 64
#define MTOT (BB*TT)            // 4096
#define NQKV (CC + 2*NKV*HD)    // 3072 (fused q|k|v columns)

typedef unsigned short u16;
typedef __attribute__((ext_vector_type(8))) short bf16x8;
typedef __attribute__((ext_vector_type(4))) float f32x4;

// fp32 -> bf16 (round-to-nearest-even), bit-twiddle form
__device__ __forceinline__ u16 f2bf(float f) {
  unsigned u = __float_as_uint(f);
  unsigned r = (u + 0x7FFFu + ((u >> 16) & 1u)) >> 16;
  return (u16)r;
}
// fp32 -> bf16 via HW convert (RNE, identical results; fewer VALU ops)
__device__ __forceinline__ u16 f2bf_hw(float f) {
  __hip_bfloat16 h = __float2bfloat16(f);
  return *reinterpret_cast<const u16*>(&h);
}
__device__ __forceinline__ float bf2f(u16 v) {
  return __uint_as_float(((unsigned)v) << 16);
}

// async global->LDS, 16B per lane; lds base must be wave-uniform (HW adds lane*16)
__device__ __forceinline__ void gl_lds16(const void* g, void* l) {
  __builtin_amdgcn_global_load_lds(
      (const __attribute__((address_space(1))) unsigned int*)g,
      (__attribute__((address_space(3))) unsigned int*)l, 16, 0, 0);
}

// ---------------------------------------------------------------------------
// prep: fused x->bf16 convert (z=4) + 4 weight transposes (z=0..3).
// grid (64, 64, 5), block (32, 8).
// ---------------------------------------------------------------------------
__global__ __launch_bounds__(256) void prep(
    const float* __restrict__ x, const float* __restrict__ Wq,
    const float* __restrict__ Wk, const float* __restrict__ Wv,
    const float* __restrict__ Wo, u16* __restrict__ xb,
    u16* __restrict__ Wt, u16* __restrict__ Wot) {
  const int z = blockIdx.z;
  const int tx = threadIdx.x, ty = threadIdx.y;
  if (z == 4) {
    const int tid = ty * 32 + tx;
    const int i = (blockIdx.y * 64 + blockIdx.x) * 256 + tid;  // 8-elem group
    const float4* s4 = (const float4*)x;
    float4 a = s4[(size_t)i * 2], b = s4[(size_t)i * 2 + 1];
    bf16x8 o;
    o[0] = (short)f2bf(a.x); o[1] = (short)f2bf(a.y);
    o[2] = (short)f2bf(a.z); o[3] = (short)f2bf(a.w);
    o[4] = (short)f2bf(b.x); o[5] = (short)f2bf(b.y);
    o[6] = (short)f2bf(b.z); o[7] = (short)f2bf(b.w);
    ((bf16x8*)xb)[i] = o;
    return;
  }
  const float* W; u16* dst; int N; int row_off;
  if (z == 0)      { W = Wq; dst = Wt;  N = 2048; row_off = 0; }
  else if (z == 1) { W = Wk; dst = Wt;  N = 512;  row_off = 2048; }
  else if (z == 2) { W = Wv; dst = Wt;  N = 512;  row_off = 2560; }
  else             { W = Wo; dst = Wot; N = 2048; row_off = 0; }
  const int n0 = blockIdx.x * 32, k0 = blockIdx.y * 32;
  if (n0 >= N) return;
  __shared__ float tile[32][33];
#pragma unroll
  for (int i = 0; i < 4; ++i)
    tile[ty + 8 * i][tx] = W[(size_t)(k0 + ty + 8 * i) * N + n0 + tx];
  __syncthreads();
#pragma unroll
  for (int i = 0; i < 4; ++i)
    dst[(size_t)(row_off + n0 + ty + 8 * i) * CC + k0 + tx] =
        f2bf(tile[tx][ty + 8 * i]);
}

// ---------------------------------------------------------------------------
// 256x256 8-phase bf16 MFMA GEMM (m201-style template, plain HIP).
// Verified r2: conflicts ~0, swizzle byte^=((row&7)<<4) both sides.
// ---------------------------------------------------------------------------
__global__ __launch_bounds__(512, 2) void gemm_8ph(
    const u16* __restrict__ A, const u16* __restrict__ Bt,
    const float* __restrict__ bias, float* __restrict__ C,
    int M, int N, int K, int out_bf16) {
  __shared__ u16 As[32768];   // 2 x (256x64) bf16 = 2 x 32 KB
  __shared__ u16 Bs[32768];
  const int tid = threadIdx.x;
  const int w = tid >> 6, lane = tid & 63;
  const int quad = lane >> 4, lo = lane & 15;
  const int wm = w >> 2, wn = w & 3;          // 2M x 4N wave grid
  const int bm = blockIdx.y * 256, bn = blockIdx.x * 256;
  const int NT = K >> 6;                      // K-tiles of 64 (NT >= 2)

  const u16* agp[2][2]; const u16* bgp[2][2];
#pragma unroll
  for (int h = 0; h < 2; ++h)
#pragma unroll
    for (int j = 0; j < 2; ++j) {
      const unsigned X = (unsigned)h * 16384u +
                         (unsigned)((w * 2 + j) * 64 + lane) * 16u;
      const int row = (int)(X >> 7);
      const int ce = (int)(((X & 127u) ^ (((X >> 7) & 7u) << 4)) >> 1);
      agp[h][j] = A  + (size_t)(bm + row) * K + ce;
      bgp[h][j] = Bt + (size_t)(bn + row) * K + ce;
    }
  char* const lAs = (char*)As;
  char* const lBs = (char*)Bs;
  const int woff = w * 2048;

#define STGA(hh, bufp, kt) do { \
    gl_lds16(agp[hh][0] + (size_t)(kt) * 64, lAs + (bufp) * 32768 + (hh) * 16384 + woff); \
    gl_lds16(agp[hh][1] + (size_t)(kt) * 64, lAs + (bufp) * 32768 + (hh) * 16384 + woff + 1024); \
  } while (0)
#define STGB(hh, bufp, kt) do { \
    gl_lds16(bgp[hh][0] + (size_t)(kt) * 64, lBs + (bufp) * 32768 + (hh) * 16384 + woff); \
    gl_lds16(bgp[hh][1] + (size_t)(kt) * 64, lBs + (bufp) * 32768 + (hh) * 16384 + woff + 1024); \
  } while (0)

  const int sw  = (lo & 7) << 4;
  const int co0 = (quad * 16) ^ sw;
  const int co1 = (64 + quad * 16) ^ sw;
  const int aRB = (wm * 128 + lo) * 128;      // + qr*8192 + i*2048
  const int bRB = (wn * 64 + lo) * 128;       // + qc*4096 + j*2048

  f32x4 acc[8][4];
#pragma unroll
  for (int ri = 0; ri < 8; ++ri)
#pragma unroll
    for (int ci = 0; ci < 4; ++ci)
#pragma unroll
      for (int r = 0; r < 4; ++r) acc[ri][ci][r] = 0.f;

  STGA(0, 0, 0); STGA(1, 0, 0); STGB(0, 0, 0); STGB(1, 0, 0);
  STGB(0, 1, 1); STGB(1, 1, 1); STGA(0, 1, 1);
  asm volatile("s_waitcnt vmcnt(6)" ::: "memory");
  __builtin_amdgcn_s_barrier();

  for (int t = 0; t < NT; ++t) {
    const int pa = t & 1;
    const char* Ab = lAs + pa * 32768 + aRB;
    const char* Bb = lBs + pa * 32768 + bRB;
    bf16x8 a[4][2], b0[2][2], b1[2][2];

    // ---- phase 0: quadrant (qr=0, qc=0) --------------------------------
#pragma unroll
    for (int i = 0; i < 4; ++i) {
      a[i][0] = *(const bf16x8*)(Ab + i * 2048 + co0);
      a[i][1] = *(const bf16x8*)(Ab + i * 2048 + co1);
    }
#pragma unroll
    for (int j = 0; j < 2; ++j) {
      b0[j][0] = *(const bf16x8*)(Bb + j * 2048 + co0);
      b0[j][1] = *(const bf16x8*)(Bb + j * 2048 + co1);
    }
    if (t + 1 < NT) STGA(1, (t + 1) & 1, t + 1);
    __builtin_amdgcn_s_barrier();
    asm volatile("s_waitcnt lgkmcnt(0)");
    __builtin_amdgcn_s_setprio(1);
#pragma unroll
    for (int i = 0; i < 4; ++i)
#pragma unroll
      for (int j = 0; j < 2; ++j) {
        acc[i][j] = __builtin_amdgcn_mfma_f32_16x16x32_bf16(a[i][0], b0[j][0], acc[i][j], 0, 0, 0);
        acc[i][j] = __builtin_amdgcn_mfma_f32_16x16x32_bf16(a[i][1], b0[j][1], acc[i][j], 0, 0, 0);
      }
    __builtin_amdgcn_s_setprio(0);
    __builtin_amdgcn_s_barrier();

    // ---- phase 1: quadrant (qr=0, qc=1) --------------------------------
#pragma unroll
    for (int j = 0; j < 2; ++j) {
      b1[j][0] = *(const bf16x8*)(Bb + 4096 + j * 2048 + co0);
      b1[j][1] = *(const bf16x8*)(Bb + 4096 + j * 2048 + co1);
    }
    __builtin_amdgcn_s_barrier();
    asm volatile("s_waitcnt lgkmcnt(0)");
    __builtin_amdgcn_s_setprio(1);
#pragma unroll
    for (int i = 0; i < 4; ++i)
#pragma unroll
      for (int j = 0; j < 2; ++j) {
        acc[i][2 + j] = __builtin_amdgcn_mfma_f32_16x16x32_bf16(a[i][0], b1[j][0], acc[i][2 + j], 0, 0, 0);
        acc[i][2 + j] = __builtin_amdgcn_mfma_f32_16x16x32_bf16(a[i][1], b1[j][1], acc[i][2 + j], 0, 0, 0);
      }
    __builtin_amdgcn_s_setprio(0);
    __builtin_amdgcn_s_barrier();

    // ---- phase 2: quadrant (qr=1, qc=1) --------------------------------
#pragma unroll
    for (int i = 0; i < 4; ++i) {
      a[i][0] = *(const bf16x8*)(Ab + 8192 + i * 2048 + co0);
      a[i][1] = *(const bf16x8*)(Ab + 8192 + i * 2048 + co1);
    }
    if (t + 2 < NT) STGB(0, pa, t + 2);
    __builtin_amdgcn_s_barrier();
    asm volatile("s_waitcnt lgkmcnt(0)");
    __builtin_amdgcn_s_setprio(1);
#pragma unroll
    for (int i = 0; i < 4; ++i)
#pragma unroll
      for (int j = 0; j < 2; ++j) {
        acc[4 + i][2 + j] = __builtin_amdgcn_mfma_f32_16x16x32_bf16(a[i][0], b1[j][0], acc[4 + i][2 + j], 0, 0, 0);
        acc[4 + i][2 + j] = __builtin_amdgcn_mfma_f32_16x16x32_bf16(a[i][1], b1[j][1], acc[4 + i][2 + j], 0, 0, 0);
      }
    __builtin_amdgcn_s_setprio(0);
    __builtin_amdgcn_s_barrier();

    // ---- phase 3: quadrant (qr=1, qc=0); counted wait ------------------
    if (t + 2 < NT) { STGB(1, pa, t + 2); STGA(0, pa, t + 2); }
    if (t + 2 < NT)      asm volatile("s_waitcnt vmcnt(6)" ::: "memory");
    else if (t + 1 < NT) asm volatile("s_waitcnt vmcnt(0)" ::: "memory");
    __builtin_amdgcn_s_barrier();
    asm volatile("s_waitcnt lgkmcnt(0)");
    __builtin_amdgcn_s_setprio(1);
#pragma unroll
    for (int i = 0; i < 4; ++i)
#pragma unroll
      for (int j = 0; j < 2; ++j) {
        acc[4 + i][j] = __builtin_amdgcn_mfma_f32_16x16x32_bf16(a[i][0], b0[j][0], acc[4 + i][j], 0, 0, 0);
        acc[4 + i][j] = __builtin_amdgcn_mfma_f32_16x16x32_bf16(a[i][1], b0[j][1], acc[4 + i][j], 0, 0, 0);
      }
    __builtin_amdgcn_s_setprio(0);
    __builtin_amdgcn_s_barrier();
  }
#undef STGA
#undef STGB

  const int rbase = bm + wm * 128;
  const int cbase = bn + wn * 64;
#pragma unroll
  for (int ri = 0; ri < 8; ++ri)
#pragma unroll
    for (int ci = 0; ci < 4; ++ci) {
      const int col = cbase + ci * 16 + lo;
      const float bv = bias ? bias[col] : 0.f;
#pragma unroll
      for (int r = 0; r < 4; ++r) {
        const int row = rbase + ri * 16 + quad * 4 + r;
        const float v = acc[ri][ci][r] + bv;
        if (out_bf16) ((u16*)C)[(size_t)row * N + col] = f2bf(v);
        else          C[(size_t)row * N + col] = v;
      }
    }
}

// ---------------------------------------------------------------------------
// 256x128 2-phase bf16 MFMA GEMM — grid-fill variant for the out-proj
// (N=2048 -> 16x16 = 256 blocks = 1/CU). Verified r4.
// ---------------------------------------------------------------------------
__global__ __launch_bounds__(512, 2) void gemm_n128(
    const u16* __restrict__ A, const u16* __restrict__ Bt,
    const float* __restrict__ bias, float* __restrict__ C,
    int M, int N, int K, int out_bf16) {
  __shared__ u16 As[32768];   // 2 x (256x64) bf16
  __shared__ u16 Bs[16384];   // 2 x (128x64) bf16
  const int tid = threadIdx.x;
  const int w = tid >> 6, lane = tid & 63;
  const int quad = lane >> 4, lo = lane & 15;
  const int wm = w >> 1, wn = w & 1;          // 4M x 2N wave grid
  const int bm = blockIdx.y * 256, bn = blockIdx.x * 128;
  const int NT = K >> 6;                      // K-tiles of 64 (NT >= 3)

  const u16* agp[2][2];
#pragma unroll
  for (int h = 0; h < 2; ++h)
#pragma unroll
    for (int j = 0; j < 2; ++j) {
      const unsigned X = (unsigned)h * 16384u +
                         (unsigned)((w * 2 + j) * 64 + lane) * 16u;
      const int row = (int)(X >> 7);
      const int ce = (int)(((X & 127u) ^ (((X >> 7) & 7u) << 4)) >> 1);
      agp[h][j] = A + (size_t)(bm + row) * K + ce;
    }
  const u16* bgp[2];
#pragma unroll
  for (int j = 0; j < 2; ++j) {
    const unsigned X = (unsigned)((w * 2 + j) * 64 + lane) * 16u;
    const int row = (int)(X >> 7);
    const int ce = (int)(((X & 127u) ^ (((X >> 7) & 7u) << 4)) >> 1);
    bgp[j] = Bt + (size_t)(bn + row) * K + ce;
  }
  char* const lAs = (char*)As;
  char* const lBs = (char*)Bs;
  const int woff = w * 2048;

#define STGA_(hh, bufp, kt) do { \
    gl_lds16(agp[hh][0] + (size_t)(kt) * 64, lAs + (bufp) * 32768 + (hh) * 16384 + woff); \
    gl_lds16(agp[hh][1] + (size_t)(kt) * 64, lAs + (bufp) * 32768 + (hh) * 16384 + woff + 1024); \
  } while (0)
#define STGB_(bufp, kt) do { \
    gl_lds16(bgp[0] + (size_t)(kt) * 64, lBs + (bufp) * 16384 + woff); \
    gl_lds16(bgp[1] + (size_t)(kt) * 64, lBs + (bufp) * 16384 + woff + 1024); \
  } while (0)

  const int sw  = (lo & 7) << 4;
  const int co0 = (quad * 16) ^ sw;
  const int co1 = (64 + quad * 16) ^ sw;
  const int aRB = (wm * 64 + lo) * 128;       // + i*2048
  const int bRB = (wn * 64 + lo) * 128;       // + ci*2048

  f32x4 acc[4][4];
#pragma unroll
  for (int i = 0; i < 4; ++i)
#pragma unroll
    for (int ci = 0; ci < 4; ++ci)
#pragma unroll
      for (int r = 0; r < 4; ++r) acc[i][ci][r] = 0.f;

  STGA_(0, 0, 0); STGA_(1, 0, 0); STGB_(0, 0);
  STGB_(1, 1); STGA_(0, 1, 1);
  asm volatile("s_waitcnt vmcnt(4)" ::: "memory");
  __builtin_amdgcn_s_barrier();

  for (int t = 0; t < NT; ++t) {
    const int pa = t & 1;
    const char* Ab = lAs + pa * 32768 + aRB;
    const char* Bb = lBs + pa * 16384 + bRB;
    bf16x8 a[4][2], b[4][2];
#pragma unroll
    for (int i = 0; i < 4; ++i) {
      a[i][0] = *(const bf16x8*)(Ab + i * 2048 + co0);
      a[i][1] = *(const bf16x8*)(Ab + i * 2048 + co1);
    }
#pragma unroll
    for (int ci = 0; ci < 4; ++ci) {
      b[ci][0] = *(const bf16x8*)(Bb + ci * 2048 + co0);
      b[ci][1] = *(const bf16x8*)(Bb + ci * 2048 + co1);
    }
    if (t + 1 < NT) STGA_(1, (t + 1) & 1, t + 1);
    asm volatile("s_waitcnt lgkmcnt(0)");   // own reads done BEFORE barrier
    __builtin_amdgcn_s_barrier();           // -> all waves' reads of buf pa done
    __builtin_amdgcn_s_setprio(1);
#pragma unroll
    for (int i = 0; i < 4; ++i)
#pragma unroll
      for (int ci = 0; ci < 2; ++ci) {
        acc[i][ci] = __builtin_amdgcn_mfma_f32_16x16x32_bf16(a[i][0], b[ci][0], acc[i][ci], 0, 0, 0);
        acc[i][ci] = __builtin_amdgcn_mfma_f32_16x16x32_bf16(a[i][1], b[ci][1], acc[i][ci], 0, 0, 0);
      }
    __builtin_amdgcn_s_setprio(0);
    if (t + 2 < NT) { STGB_(pa, t + 2); STGA_(0, pa, t + 2); }
    if (t + 2 < NT)      asm volatile("s_waitcnt vmcnt(4)" ::: "memory");
    else if (t + 1 < NT) asm volatile("s_waitcnt vmcnt(0)" ::: "memory");
    __builtin_amdgcn_s_setprio(1);
#pragma unroll
    for (int i = 0; i < 4; ++i)
#pragma unroll
      for (int ci = 2; ci < 4; ++ci) {
        acc[i][ci] = __builtin_amdgcn_mfma_f32_16x16x32_bf16(a[i][0], b[ci][0], acc[i][ci], 0, 0, 0);
        acc[i][ci] = __builtin_amdgcn_mfma_f32_16x16x32_bf16(a[i][1], b[ci][1], acc[i][ci], 0, 0, 0);
      }
    __builtin_amdgcn_s_setprio(0);
    __builtin_amdgcn_s_barrier();           // next iter reads need all DMAs in
  }
#undef STGA_
#undef STGB_

  const int rbase = bm + wm * 64;
  const int cbase = bn + wn * 64;
#pragma unroll
  for (int i = 0; i < 4; ++i)
#pragma unroll
    for (int ci = 0; ci < 4; ++ci) {
      const int col = cbase + ci * 16 + lo;
      const float bv = bias ? bias[col] : 0.f;
#pragma unroll
      for (int r = 0; r < 4; ++r) {
        const int row = rbase + i * 16 + quad * 4 + r;
        const float v = acc[i][ci][r] + bv;
        if (out_bf16) ((u16*)C)[(size_t)row * N + col] = f2bf(v);
        else          C[(size_t)row * N + col] = v;
      }
    }
}

// ---------------------------------------------------------------------------
// FUSED qkv_post + v_transpose. grid (B*T, 6), block 256.
//   y in [0,5): RMSNorm + RoPE for head (y*4 + wave), one wave per (b,t,head).
//   y == 5:     v-transpose; blocks x in [0,2048) do the original
//               v_transpose grid (64, 4, 8) remapped as
//               t0=(x&63)*32, d0=((x>>6)&3)*32, p=x>>8; inner code identical.
// Saves one serialized kernel launch (gap-hypothesis probe).
// ---------------------------------------------------------------------------
__global__ __launch_bounds__(256) void qkv_post(
    const u16* __restrict__ qkv_lin, const float* __restrict__ cosp,
    const float* __restrict__ sinp, u16* __restrict__ q, u16* __restrict__ k,
    u16* __restrict__ vt) {
  __shared__ u16 tile[32][33];
  if (blockIdx.y == 5) {
    const int bx = blockIdx.x;
    if (bx >= 2048) return;
    const int t0 = (bx & 63) * 32, d0 = ((bx >> 6) & 3) * 32;
    const int p = bx >> 8;              // b*NKV + kv
    const int b = p >> 2, kv = p & 3;
    const int tx = threadIdx.x & 31, ty = threadIdx.x >> 5;
#pragma unroll
    for (int i = 0; i < 4; ++i)
      tile[ty + 8 * i][tx] =
          qkv_lin[(size_t)(b * TT + t0 + ty + 8 * i) * NQKV + CC + NKV * HD + kv * HD + d0 + tx];
    __syncthreads();
    const int tperm = ((tx >> 2) & 3) * 8 + (tx & 3) + 4 * ((tx >> 4) & 1);
#pragma unroll
    for (int i = 0; i < 4; ++i)
      vt[((size_t)p * HD + d0 + ty + 8 * i) * TT + t0 + tperm] = tile[tx][ty + 8 * i];
    return;
  }
  const int bt = blockIdx.x;
  const int hh = blockIdx.y * 4 + (threadIdx.x >> 6);   // 0..19
  const int lane = threadIdx.x & 63;
  const int t = bt & (TT - 1), b = bt >> 11;
  const int col = (hh < NH) ? hh * HD : CC + (hh - NH) * HD;
  const u16* src = qkv_lin + (size_t)bt * NQKV + col;
  float v1 = bf2f(src[lane]), v2 = bf2f(src[lane + 64]);
  float ss = v1 * v1 + v2 * v2;
#pragma unroll
  for (int mm = 1; mm < 64; mm <<= 1) ss += __shfl_xor(ss, mm, 64);
  float rms = rsqrtf(ss * (1.f / 128.f) + 1.1920929e-7f);
  float c = cosp[t * HALF + lane], s = sinp[t * HALF + lane];
  float o1 = v1 * rms * c - v2 * rms * s;
  float o2 = v1 * rms * s + v2 * rms * c;
  if (hh < NH) {
    u16* dst = q + (((size_t)(b * NH + hh)) * TT + t) * HD;
    dst[lane] = f2bf(o1); dst[lane + 64] = f2bf(o2);
  } else {
    u16* dst = k + (((size_t)(b * NKV + (hh - NH))) * TT + t) * HD;
    dst[lane] = f2bf(o1); dst[lane + 64] = f2bf(o2);
  }
}

// ---------------------------------------------------------------------------
// S^T softmax + A-fragment pack, all in registers (v5-verified math).
// f2bf_hw (v_cvt) in the pack — correctness-proven in r6's run.
// ---------------------------------------------------------------------------
__device__ __forceinline__ void softmax_pack(
    const f32x4* sacc, float& l_lane, bf16x8* ap, int rowq, int t0,
    bool diag, int quad) {
  const float cc = 0.12751744050808612f;   // log2(e)/sqrt(128)
  float e[4][4];
  if (diag) {
#pragma unroll
    for (int ct = 0; ct < 4; ++ct)
#pragma unroll
      for (int r = 0; r < 4; ++r) {
        float v = __builtin_amdgcn_exp2f(sacc[ct][r] * cc);
        if (t0 + ct * 16 + quad * 4 + r > rowq) v = 0.f;
        l_lane += v; e[ct][r] = v;
      }
  } else {
#pragma unroll
    for (int ct = 0; ct < 4; ++ct)
#pragma unroll
      for (int r = 0; r < 4; ++r) {
        float v = __builtin_amdgcn_exp2f(sacc[ct][r] * cc);
        l_lane += v; e[ct][r] = v;
      }
  }
#pragma unroll
  for (int k2 = 0; k2 < 2; ++k2) {
    bf16x8 ch;
#pragma unroll
    for (int j = 0; j < 8; ++j)
      ch[j] = (short)f2bf_hw(e[k2 * 2 + (j >> 2)][j & 3]);
    ap[k2] = ch;
  }
}

// ---------------------------------------------------------------------------
// MFMA flash attention v7 (r5-verified, 73.1 µs): rb-split, 8 waves,
// 64 KB double-buffered LDS -> 2 blocks/CU (cross-block overlap is the
// latency-hiding mechanism — r6's 96 KB variant at 1 block/CU was 1.8x worse).
// ---------------------------------------------------------------------------
__global__ __launch_bounds__(512, 4) void attn_mfma(
    const u16* __restrict__ Qb, const u16* __restrict__ Kb,
    const u16* __restrict__ Vt, u16* __restrict__ Y) {
  __shared__ u16 Ks[2][8192];   // 16 sets (ct*4+kc) x 512, dbuf
  __shared__ u16 Vs[2][8192];   // 16 sets (dt*2+k2) x 512, dbuf

  const int qt = blockIdx.x;    // pair (qt, 31-qt)
  const int bh = blockIdx.y;
  const int b = bh >> 4, h = bh & 15, kvh = h >> 2;
  const int tid = threadIdx.x;
  const int wave = tid >> 6, lane = tid & 63;
  const int wg = wave >> 2, wv = wave & 3;   // wg: 0 = tile A, 1 = tile B
  const int quad = lane >> 4, lo = lane & 15;

  const int rows = (wg == 0) ? qt * 64 : (31 - qt) * 64;
  const u16* Qg = Qb + (size_t)(b * NH + h) * TT * HD;
  const u16* Kg = Kb + (size_t)(b * NKV + kvh) * TT * HD;
  const u16* Vg = Vt + (size_t)(b * NKV + kvh) * HD * TT;

  // Q fragments, used as MFMA B-operand (n=lo -> q-row, k=quad*8+j)
  bf16x8 aq[4];
#pragma unroll
  for (int kc = 0; kc < 4; ++kc)
    aq[kc] = *(const bf16x8*)(Qg + (size_t)(rows + wv * 16 + lo) * HD + kc * 32 + quad * 8);

  // staging: wave stages K sets {wave*2, wave*2+1} and V sets {wave*2, wave*2+1}
  const u16* kgp[2]; const u16* vgp[2];
  u16* klp[2][2]; u16* vlp[2][2];
#pragma unroll
  for (int c = 0; c < 2; ++c) {
    const int s = wave * 2 + c;          // 0..15
    const int ct = s >> 2, kq = s & 3;
    kgp[c] = Kg + (size_t)(ct * 16 + lo) * HD + kq * 32 + quad * 8;
    const int dt = s >> 1, k2 = s & 1;
    vgp[c] = Vg + (size_t)(dt * 16 + lo) * TT + k2 * 32 + quad * 8;
    klp[0][c] = &Ks[0][s * 512]; klp[1][c] = &Ks[1][s * 512];
    vlp[0][c] = &Vs[0][s * 512]; vlp[1][c] = &Vs[1][s * 512];
  }

  f32x4 oacc[8];
#pragma unroll
  for (int dt = 0; dt < 8; ++dt)
#pragma unroll
    for (int r = 0; r < 4; ++r) oacc[dt][r] = 0.f;
  float l_lane = 0.f;

  const int ntiles = 32 - qt;
  const int rowq = rows + wv * 16 + lo;   // this lane's q-row

  // prologue: stage tile 0 -> buf 0
#pragma unroll
  for (int c = 0; c < 2; ++c) {
    gl_lds16(kgp[c], klp[0][c]); kgp[c] += 64 * HD;
    gl_lds16(vgp[c], vlp[0][c]); vgp[c] += 64;
  }

  for (int nt = 0; nt < ntiles; ++nt) {
    const int par = nt & 1;
    __syncthreads();  // tile nt landed (vmcnt drained); buf[par^1] readers done
    if (nt + 1 < ntiles) {
#pragma unroll
      for (int c = 0; c < 2; ++c) {
        gl_lds16(kgp[c], klp[par ^ 1][c]); kgp[c] += 64 * HD;
        gl_lds16(vgp[c], vlp[par ^ 1][c]); vgp[c] += 64;
      }
    }
    const bool act = (wg == 1) || (nt <= qt);
    if (act) {
      const u16* ksb = Ks[par];
      const u16* vsb = Vs[par];
      const int t0 = nt * 64;

      // S^T = K Q^T: D row (quad*4+r) = kv, col (lo) = q-row
      f32x4 sacc[4];
#pragma unroll
      for (int ct = 0; ct < 4; ++ct)
#pragma unroll
        for (int r = 0; r < 4; ++r) sacc[ct][r] = 0.f;
      __builtin_amdgcn_s_setprio(1);
#pragma unroll
      for (int ct = 0; ct < 4; ++ct)
#pragma unroll
        for (int kc = 0; kc < 4; ++kc) {
          bf16x8 bk = *(const bf16x8*)&ksb[(ct * 4 + kc) * 512 + lane * 8];
          sacc[ct] = __builtin_amdgcn_mfma_f32_16x16x32_bf16(bk, aq[kc], sacc[ct], 0, 0, 0);
        }
      __builtin_amdgcn_s_setprio(0);

      // softmax + register P pack
      bf16x8 ap[2];
      softmax_pack(sacc, l_lane, ap, rowq, t0, t0 + 63 > rows + wv * 16, quad);

      // O += P @ V  (V already in permuted kv order matching the pack)
      __builtin_amdgcn_s_setprio(1);
#pragma unroll
      for (int dt = 0; dt < 8; ++dt)
#pragma unroll
        for (int k2 = 0; k2 < 2; ++k2) {
          bf16x8 bv = *(const bf16x8*)&vsb[(dt * 2 + k2) * 512 + lane * 8];
          oacc[dt] = __builtin_amdgcn_mfma_f32_16x16x32_bf16(ap[k2], bv, oacc[dt], 0, 0, 0);
        }
      __builtin_amdgcn_s_setprio(0);
    }
  }

  // epilogue: l for q-row `lo` -> reduce over quad lanes; fetch per-output-row
  float l = l_lane;
  l += __shfl_xor(l, 16, 64);
  l += __shfl_xor(l, 32, 64);
  l = 1.f / l;                       // valid at lane lo for row lo (all quads)
  float linv[4];
#pragma unroll
  for (int r = 0; r < 4; ++r)
    linv[r] = __shfl(l, quad * 4 + r, 64);   // row quad*4+r lives at lane quad*4+r
  const size_t row0 = (size_t)b * TT + rows + wv * 16 + quad * 4;
#pragma unroll
  for (int dt = 0; dt < 8; ++dt)
#pragma unroll
    for (int r = 0; r < 4; ++r)
      Y[(row0 + r) * CC + h * HD + dt * 16 + lo] = f2bf(oacc[dt][r] * linv[r]);
}

// ---------------------------------------------------------------------------
// kernel_launch. ws layout (bytes):
//   [0,16M):   xb (bf16 x)            -> later qb_buf (bf16 q, B,H,T,D)
//   [16M,28M): Wt (bf16 qkv^T)        -> later kb (4M) + vt (8M)
//   [28M,52M): qkv_lin bf16 (M x 3072)-> first 16M later y (bf16, M x C)
//   [52M,60M): Wot (bf16 Wo^T)
// ---------------------------------------------------------------------------
extern "C" void kernel_launch(void* const* d_in, const int* in_sizes, int n_in,
                              void* d_out, int out_size, void* d_ws, size_t ws_size,
                              hipStream_t stream) {
  (void)in_sizes; (void)n_in; (void)out_size; (void)ws_size;
  const float* x    = (const float*)d_in[0];
  const float* cosp = (const float*)d_in[1];
  const float* sinp = (const float*)d_in[2];
  const float* Wq   = (const float*)d_in[3];
  const float* Wk   = (const float*)d_in[4];
  const float* Wv   = (const float*)d_in[5];
  const float* Wo   = (const float*)d_in[6];
  const float* bo   = (const float*)d_in[7];
  float* out = (float*)d_out;
  char* ws = (char*)d_ws;

  const size_t MB = 1024 * 1024;
  u16* xb      = (u16*)(ws);
  u16* Wt      = (u16*)(ws + 16 * MB);
  u16* qkv_lin = (u16*)(ws + 28 * MB);
  u16* Wot     = (u16*)(ws + 52 * MB);
  u16* qb_buf  = (u16*)(ws);             // alias xb (dead after GEMM1)
  u16* kb      = (u16*)(ws + 16 * MB);   // alias Wt
  u16* vt      = (u16*)(ws + 20 * MB);   // alias Wt+4M
  u16* y       = (u16*)(ws + 28 * MB);   // alias qkv_lin head (dead after post)

  // 1. fused convert + weight transposes
  prep<<<dim3(64, 64, 5), dim3(32, 8), 0, stream>>>(x, Wq, Wk, Wv, Wo, xb, Wt, Wot);

  // 2. fused QKV GEMM (M=4096, N=3072, K=2048), bf16 out
  gemm_8ph<<<dim3(NQKV / 256, MTOT / 256), 512, 0, stream>>>(
      xb, Wt, nullptr, (float*)qkv_lin, MTOT, NQKV, CC, 1);

  // 3. fused RMSNorm+RoPE (y<5) + V-transpose (y==5)
  qkv_post<<<dim3(MTOT, 6), 256, 0, stream>>>(qkv_lin, cosp, sinp, qb_buf, kb, vt);

  // 4. MFMA flash attention v7 -> y bf16 (M x C)
  attn_mfma<<<dim3(16, BB * NH), 512, 0, stream>>>(qb_buf, kb, vt, y);

  // 5. out-proj GEMM + bias (fp32 out) — 256x128 tiles: 256 blocks = 1/CU
  gemm_n128<<<dim3(CC / 128, MTOT / 256), 512, 0, stream>>>(
      y, Wot, bo, out, MTOT, CC, CC, 0);
}